// Round 10
// baseline (4466.825 us; speedup 1.0000x reference)
//
#include <hip/hip_runtime.h>

#define SLEN 512
#define BATCH 64
#define HID 256
#define EMB 128
#define NT 18
#define BQ 8              // batches per group
#define NGROUP 16         // 2 dirs x 8 batch-chunks
#define NSLICE 32         // producer WGs (slices of 8 units) per group
#define FB 8              // batches per feats block
#define SB 4              // timesteps per feats block
#define VROW 388          // padded LDS row stride (vh), 16B-aligned, bank-spread
#define EROW 132          // padded LDS row stride (vemb)

typedef unsigned int u32;

__device__ __forceinline__ float sigmoidf_(float v) { return 1.0f / (1.0f + expf(-v)); }
__device__ __forceinline__ u32 aload(const u32* p) {
  return __hip_atomic_load((u32*)p, __ATOMIC_RELAXED, __HIP_MEMORY_SCOPE_AGENT);
}

// ---------------------------------------------------------------------------
// Persistent bidirectional LSTM. grid = 512 blocks x 256 threads, 2 blocks/CU.
// group g = blockIdx&15 : dir = g>>3, chunk = g&7 (8 batches).
// slice rk = blockIdx>>4 (0..31): hidden units [8rk,8rk+8) -> 32 gate rows.
// Thread: r = tid&31 (gate row), kg = tid>>5 (K-group: h[32kg,32kg+32) +
// emb[16kg,16kg+16)). Wave w = tid>>6 spans kg {2w,2w+1}.
//
// KEY STRUCTURE: thread tid stages h[q][k=tid]; K-group kg reads only
// k in [32kg,32kg+32) == staged by ITS OWN WAVE -> h staging needs NO
// barrier (wave lockstep + lgkmcnt). Each wave independently: pipelined-poll
// its 8 slice flags (3 outstanding loads, ~RT/3 detect) -> fetch its 64
// h-words -> ds_write -> GEMM. Only the K-reduce crosses waves: ONE
// __syncthreads per step; `red` double-buffered by step parity (WAR chain:
// wave w's red-write at t+2 is after SYNC_B(t+1), which is after wave0's
// red-read(t)).
// Producer (wave0): gates -> h stores (relaxed AGENT, write-through) ->
// vmcnt(0) -> per-slice flag word (no RMW, no relay).
// ---------------------------------------------------------------------------
__global__ __launch_bounds__(256, 2) void lstm_kernel(
    const int* __restrict__ x, const float* __restrict__ embed,
    const float* __restrict__ Wih_f, const float* __restrict__ Whh_f,
    const float* __restrict__ bih_f, const float* __restrict__ bhh_f,
    const float* __restrict__ Wih_b, const float* __restrict__ Whh_b,
    const float* __restrict__ bih_b, const float* __restrict__ bhh_b,
    const float* __restrict__ h0, const float* __restrict__ c0,
    float* __restrict__ h_hist, u32* __restrict__ flags)
{
  const int g   = blockIdx.x & 15;
  const int rk  = blockIdx.x >> 4;   // 0..31
  const int dir = g >> 3;
  const int b0  = (g & 7) * BQ;
  const int tid = threadIdx.x;
  const int kg  = tid >> 5;          // 0..7
  const int r   = tid & 31;          // gate row
  const int gi  = r >> 3;
  const int uo  = r & 7;
  const int grow = gi * 256 + rk * 8 + uo;
  const int wv  = tid >> 6;          // wave 0..3

  const float* Wih = dir ? Wih_b : Wih_f;
  const float* Whh = dir ? Whh_b : Whh_f;
  const float* bih = dir ? bih_b : bih_f;
  const float* bhh = dir ? bhh_b : bhh_f;

  // weights: c 0..7 -> Whh[grow][32kg+4c] ; c 8..11 -> Wih[grow][16kg+4(c-8)]
  float4 wreg[12];
#pragma unroll
  for (int c = 0; c < 8; ++c)
    wreg[c] = *(const float4*)(Whh + (size_t)grow * 256 + kg * 32 + c * 4);
#pragma unroll
  for (int c = 0; c < 4; ++c)
    wreg[8 + c] = *(const float4*)(Wih + (size_t)grow * 128 + kg * 16 + c * 4);

  __shared__ float vh[BQ * VROW];        // 12.4 KB : h(t-1), col k = tid
  __shared__ float vemb[BQ * EROW];      // 4.2 KB  : emb(t)
  __shared__ float red[2][4][BQ][33];    // 8.4 KB  : parity-double-buffered

  // gates-lane state (wave0, tid<64): b=tid>>3, u=tid&7
  float bias4[4];
  float creg = 0.0f;
  if (tid < 64) {
    int u = tid & 7, b = tid >> 3;
#pragma unroll
    for (int gg = 0; gg < 4; ++gg) {
      int rr = gg * 256 + rk * 8 + u;
      bias4[gg] = bih[rr] + bhh[rr];
    }
    creg = c0[(size_t)(dir * BATCH + b0 + b) * HID + rk * 8 + u];
  }

  // emb staging mapping: lane covers (q = tid&7, ec = 32*wv + 4*((tid>>3)&7))
  const int qe = tid & 7;
  const int ec = 32 * wv + 4 * ((tid >> 3) & 7);

  // prologue: ev = emb(step 0), xv = x index for step 1
  float4 ev = *(const float4*)(embed +
               (size_t)x[(b0 + qe) * SLEN + (dir ? SLEN - 1 : 0)] * EMB + ec);
  int xv = x[(b0 + qe) * SLEN + (dir ? SLEN - 2 : 1)];

  for (int it = 0; it < SLEN; ++it) {
    const int t = dir ? (SLEN - 1 - it) : it;

    // ---- stage emb(t) (wave-local; WAR-safe by program order in-wave) ----
    *(float4*)&vemb[qe * EROW + ec] = ev;

    // ---- poll my slice flag (3-deep pipelined) + fetch h(t-1) ------------
    u32 hw[BQ];
    if (it == 0) {
      const u32* hs = (const u32*)(h0 + (size_t)(dir * BATCH + b0) * HID);
#pragma unroll
      for (int i = 0; i < BQ; ++i) hw[i] = hs[i * 256 + tid];
    } else {
      const u32* fp = flags + ((size_t)g * SLEN + (it - 1)) * NSLICE + (tid >> 3);
      u32 v0 = aload(fp), v1 = aload(fp), v2 = aload(fp);
      int sp = 0;
      while (!__all(v0 != 0) && ++sp < (1 << 13)) {
        v0 = v1; v1 = v2; v2 = aload(fp);
      }
      asm volatile("" ::: "memory");   // no hoisting of h loads above detect
      const int tp = dir ? (t + 1) : (t - 1);
      const u32* hs = (const u32*)(h_hist +
                       ((size_t)(dir * SLEN + tp) * BATCH + b0) * HID);
#pragma unroll
      for (int i = 0; i < BQ; ++i) hw[i] = aload(hs + i * 256 + tid);
    }
#pragma unroll
    for (int i = 0; i < BQ; ++i) *(u32*)&vh[i * VROW + tid] = hw[i];
    // no barrier: this wave's GEMM reads only k in [64wv,64wv+64) == staged
    // by this wave; lgkmcnt + lockstep make it visible.

    // ---- GEMM: h part, emb/x prefetch, emb part --------------------------
    float acc[BQ];
#pragma unroll
    for (int b = 0; b < BQ; ++b) acc[b] = 0.0f;
    const int kb = kg * 32;
#pragma unroll
    for (int c = 0; c < 8; ++c) {
      float4 w4 = wreg[c];
#pragma unroll
      for (int q = 0; q < BQ; ++q) {
        float4 v4 = *(const float4*)&vh[q * VROW + kb + c * 4];  // broadcast
        acc[q] = fmaf(w4.x, v4.x, acc[q]);
        acc[q] = fmaf(w4.y, v4.y, acc[q]);
        acc[q] = fmaf(w4.z, v4.z, acc[q]);
        acc[q] = fmaf(w4.w, v4.w, acc[q]);
      }
    }
    ev = *(const float4*)(embed + (size_t)xv * EMB + ec);   // emb for it+1
    {
      int sn = it + 2 < SLEN ? it + 2 : SLEN - 1;
      xv = x[(b0 + qe) * SLEN + (dir ? (SLEN - 1 - sn) : sn)];
    }
    const int ke = kg * 16;
#pragma unroll
    for (int c = 0; c < 4; ++c) {
      float4 w4 = wreg[8 + c];
#pragma unroll
      for (int q = 0; q < BQ; ++q) {
        float4 v4 = *(const float4*)&vemb[q * EROW + ke + c * 4]; // broadcast
        acc[q] = fmaf(w4.x, v4.x, acc[q]);
        acc[q] = fmaf(w4.y, v4.y, acc[q]);
        acc[q] = fmaf(w4.z, v4.z, acc[q]);
        acc[q] = fmaf(w4.w, v4.w, acc[q]);
      }
    }

    // ---- K-reduce: shfl pair (kg 2w|2w+1), then parity-buffered LDS ------
#pragma unroll
    for (int b = 0; b < BQ; ++b) acc[b] += __shfl_xor(acc[b], 32);
    if ((tid & 32) == 0) {
#pragma unroll
      for (int b = 0; b < BQ; ++b) red[it & 1][wv][b][r] = acc[b];
    }
    __syncthreads();                                   // SYNC_B (only barrier)

    // ---- gates + state + publish (wave0 only) ----------------------------
    if (tid < 64) {
      int b = tid >> 3, u = tid & 7;
      float s0 = bias4[0], s1 = bias4[1], s2 = bias4[2], s3 = bias4[3];
#pragma unroll
      for (int w = 0; w < 4; ++w) {
        s0 += red[it & 1][w][b][u];
        s1 += red[it & 1][w][b][8 + u];
        s2 += red[it & 1][w][b][16 + u];
        s3 += red[it & 1][w][b][24 + u];
      }
      float ig = sigmoidf_(s0);
      float fg = sigmoidf_(s1);
      float gv = tanhf(s2);
      float og = sigmoidf_(s3);
      creg = fg * creg + ig * gv;
      float hv = og * tanhf(creg);
      __hip_atomic_store(h_hist + ((size_t)(dir * SLEN + t) * BATCH + (b0 + b)) * HID
                           + rk * 8 + u,
                         hv, __ATOMIC_RELAXED, __HIP_MEMORY_SCOPE_AGENT);
      asm volatile("s_waitcnt vmcnt(0)" ::: "memory");   // h committed
      if (tid == 0)
        __hip_atomic_store(flags + ((size_t)g * SLEN + it) * NSLICE + rk, 1u,
                           __ATOMIC_RELAXED, __HIP_MEMORY_SCOPE_AGENT);
    }
    // waves 1-3 run ahead; red parity + flag-transitivity give WAR safety.
  }
}

// ---------------------------------------------------------------------------
// feats[s][b][tag] = [hf|hb] . Wc[tag] + bc[tag]
// grid = (512/4)*8 blocks (4 timesteps, 8-batch chunk), 256 threads.
// ---------------------------------------------------------------------------
__global__ __launch_bounds__(256) void feats_kernel(
    const float* __restrict__ h_hist, const float* __restrict__ Wc,
    const float* __restrict__ bc, float* __restrict__ feats)
{
  const int s0  = (blockIdx.x >> 3) * SB;
  const int b0  = (blockIdx.x & 7) * FB;
  const int tid = threadIdx.x;
  __shared__ float wc[NT * 516];    // 37.2 KB
  __shared__ float hl[FB * 516];    // 16.5 KB
  __shared__ float bcl[NT];
  if (tid < NT) bcl[tid] = bc[tid];
  for (int f = tid * 4; f < NT * 512; f += 1024) {
    float4 v = *(const float4*)(Wc + f);
    *(float4*)&wc[(f >> 9) * 516 + (f & 511)] = v;
  }
  for (int si = 0; si < SB; ++si) {
    const int s = s0 + si;
    const float* src0 = h_hist + ((size_t)s * BATCH + b0) * HID;
    const float* src1 = h_hist + ((size_t)(SLEN + s) * BATCH + b0) * HID;
    for (int f = tid * 4; f < FB * 256; f += 1024) {
      int b = f >> 8, j = f & 255;
      *(float4*)&hl[b * 516 + j]       = *(const float4*)(src0 + f);
      *(float4*)&hl[b * 516 + 256 + j] = *(const float4*)(src1 + f);
    }
    __syncthreads();
    if (tid < FB * NT) {
      int b = tid / NT, tag = tid - b * NT;
      float a = bcl[tag];
      const float* hp = &hl[b * 516];
      const float* wp = &wc[tag * 516];
#pragma unroll 8
      for (int k = 0; k < 512; k += 4) {
        float4 h4 = *(const float4*)(hp + k);
        float4 w4 = *(const float4*)(wp + k);
        a = fmaf(h4.x, w4.x, a); a = fmaf(h4.y, w4.y, a);
        a = fmaf(h4.z, w4.z, a); a = fmaf(h4.w, w4.w, a);
      }
      feats[((size_t)s * BATCH + b0 + b) * NT + tag] = a;
    }
    __syncthreads();   // WAR guard before restaging hl
  }
}

// ---------------------------------------------------------------------------
// Viterbi + backtrace, one block per batch, 64 threads (lanes 0..17 active).
// Replicates reference exactly, including add order:
//   cur = (feats[to] + trans[from][to]) + partition[from];  new_p = max(cur)
// strict > keeps the FIRST max (matches jnp.argmax). Masked bp=0, snapshot at
// t=len-1, back[len-1]=pointer overwrite, decode[S-1]=pointer.
// ---------------------------------------------------------------------------
__global__ __launch_bounds__(64) void viterbi_kernel(
    const float* __restrict__ feats, const int* __restrict__ mask,
    const float* __restrict__ trans, float* __restrict__ out)
{
  const int b = blockIdx.x;
  const int lane = threadIdx.x;
  __shared__ float tr[NT][NT + 1];
  __shared__ float part[2][NT + 2];
  __shared__ float lastp[NT + 2];
  __shared__ unsigned char bp[SLEN][20];
  __shared__ int len_s;

  for (int f = lane; f < NT * NT; f += 64) tr[f / NT][f % NT] = trans[f];
  int m = 0;
#pragma unroll
  for (int i = 0; i < 8; ++i) m += mask[b * SLEN + lane * 8 + i];
  for (int off = 32; off; off >>= 1) m += __shfl_down(m, off);
  if (lane == 0) len_s = m;
  __syncthreads();
  const int len = len_s;

  if (lane < NT) part[0][lane] = feats[(size_t)b * NT + lane] + tr[16][lane];  // START=16
  __syncthreads();

  int cur = 0;
  float fnext = (lane < NT) ? feats[((size_t)BATCH + b) * NT + lane] : 0.0f;
  int   mnext = mask[b * SLEN + 1];
  for (int t = 1; t < SLEN; ++t) {
    float fcur = fnext; int mcur = mnext;
    if (t < SLEN - 1) {
      fnext = (lane < NT) ? feats[((size_t)(t + 1) * BATCH + b) * NT + lane] : 0.0f;
      mnext = mask[b * SLEN + t + 1];
    }
    if (lane < NT) {
      float best = -3.0e38f; int bf = 0;
#pragma unroll
      for (int from = 0; from < NT; ++from) {
        float v = (fcur + tr[from][lane]) + part[cur][from];  // exact ref order
        if (v > best) { best = v; bf = from; }
      }
      part[cur ^ 1][lane] = best;          // new_p includes feats (ref semantics)
      bp[t][lane] = mcur ? (unsigned char)bf : (unsigned char)0;
      if (t == len - 1) lastp[lane] = best;
    }
    cur ^= 1;
    __syncthreads();
  }

  if (lane == 0) {
    float best = -3.0e38f; int bf = 0;
    for (int from = 0; from < NT; ++from) {
      float v = lastp[from] + tr[from][17];      // END=17
      if (v > best) { best = v; bf = from; }
    }
    out[b] = best;                                // path_score
    int ptr = bf;
    out[BATCH + (size_t)b * SLEN + (SLEN - 1)] = (float)ptr;
    for (int i = SLEN - 2; i >= 0; --i) {
      int nw = (i == len - 1) ? bf : (int)bp[i + 1][ptr];
      out[BATCH + (size_t)b * SLEN + i] = (float)nw;
      ptr = nw;
    }
  }
}

// ---------------------------------------------------------------------------
extern "C" void kernel_launch(void* const* d_in, const int* in_sizes, int n_in,
                              void* d_out, int out_size, void* d_ws, size_t ws_size,
                              hipStream_t stream) {
  const int*   x      = (const int*)  d_in[0];
  const int*   mask   = (const int*)  d_in[1];
  const float* embed  = (const float*)d_in[2];
  const float* Wih_f  = (const float*)d_in[3];
  const float* Whh_f  = (const float*)d_in[4];
  const float* bih_f  = (const float*)d_in[5];
  const float* bhh_f  = (const float*)d_in[6];
  const float* Wih_b  = (const float*)d_in[7];
  const float* Whh_b  = (const float*)d_in[8];
  const float* bih_b  = (const float*)d_in[9];
  const float* bhh_b  = (const float*)d_in[10];
  const float* Wc     = (const float*)d_in[11];
  const float* bc     = (const float*)d_in[12];
  const float* trans  = (const float*)d_in[13];
  const float* h0     = (const float*)d_in[14];
  const float* c0     = (const float*)d_in[15];
  float* out = (float*)d_out;

  // ws layout: h_hist @0 (64MB); flags and feats SHARE ws+64MB (disjoint in
  // time; flags re-zeroed each launch -> graph-replay deterministic).
  char* ws = (char*)d_ws;
  float* h_hist = (float*)ws;                                 // 64 MB
  u32*   flags  = (u32*)(ws + (size_t)67108864);              // 1 MB
  float* feats  = (float*)(ws + (size_t)67108864);            // 2.25 MB (aliases flags)

  hipMemsetAsync(flags, 0, (size_t)NGROUP * SLEN * NSLICE * sizeof(u32), stream);
  lstm_kernel<<<512, 256, 0, stream>>>(x, embed, Wih_f, Whh_f, bih_f, bhh_f,
                                       Wih_b, Whh_b, bih_b, bhh_b, h0, c0,
                                       h_hist, flags);
  feats_kernel<<<(SLEN / SB) * 8, 256, 0, stream>>>(h_hist, Wc, bc, feats);
  viterbi_kernel<<<BATCH, 64, 0, stream>>>(feats, mask, trans, out);
}

// Round 11
// 2157.425 us; speedup vs baseline: 2.0704x; 2.0704x over previous
//
#include <hip/hip_runtime.h>

#define SLEN 512
#define BATCH 64
#define HID 256
#define EMB 128
#define NT 18
#define BQ 2              // batches per group
#define NGROUP 64         // 2 dirs x 32 batch-chunks
#define NFLAG 8           // 4 slices x 2 gate-waves -> one 32B flag line
#define FB 8              // batches per feats block
#define SB 4              // timesteps per feats block

typedef unsigned int u32;

__device__ __forceinline__ float sigmoidf_(float v) { return 1.0f / (1.0f + expf(-v)); }
__device__ __forceinline__ u32 aload(const u32* p) {
  return __hip_atomic_load((u32*)p, __ATOMIC_RELAXED, __HIP_MEMORY_SCOPE_AGENT);
}

// ---------------------------------------------------------------------------
// Persistent bidirectional LSTM. grid = 256 blocks x 512 threads
// (launch_bounds(512,2) -> <=256 VGPR -> 2 waves/SIMD -> exactly 1 block/CU;
// 256 blocks = 256 CUs, all co-resident by construction).
// group g = blockIdx&63 : dir = g>>5, batch pair b0 = (g&31)*2.
// slice rk = blockIdx>>6 (0..3): hidden units [64rk,64rk+64) = 256 gate rows.
// Thread (row = tid&255, kh = tid>>8): ONE gate-row, K-half kh
// (kh=0: h k 0..191; kh=1: h k 192..255 + emb 0..127). 48 float4 weights in
// VGPRs; no K-reduce step (partials meet in LDS, summed by gate threads).
//
// Wave roles per step:
//   waves 0-5 : stage emb, poll the 8-word flag line (s_sleep backoff,
//               1 transaction), fetch 512 h words (bypass), stage -> SYNC_A
//   waves 6,7 : gates(it-1) results already published; fall to SYNC_A
//   all       : GEMM -> red[it&1] partial write -> SYNC_B
//   waves 6,7 : gates: sum 2 partials x 4 gates + bias, update c, store h
//               (relaxed AGENT), per-wave vmcnt(0), own flag word.
// Rendezvous pool = 4 slices (vs 32 in R4) -> straggler tax ~halved twice.
// ---------------------------------------------------------------------------
__global__ __launch_bounds__(512, 2) void lstm_kernel(
    const int* __restrict__ x, const float* __restrict__ embed,
    const float* __restrict__ Wih_f, const float* __restrict__ Whh_f,
    const float* __restrict__ bih_f, const float* __restrict__ bhh_f,
    const float* __restrict__ Wih_b, const float* __restrict__ Whh_b,
    const float* __restrict__ bih_b, const float* __restrict__ bhh_b,
    const float* __restrict__ h0, const float* __restrict__ c0,
    float* __restrict__ h_hist, u32* __restrict__ flags)
{
  const int g    = blockIdx.x & 63;
  const int rk   = blockIdx.x >> 6;   // 0..3
  const int dir  = g >> 5;
  const int b0   = (g & 31) * BQ;
  const int tid  = threadIdx.x;       // 0..511
  const int row  = tid & 255;         // gate row within slice
  const int kh   = tid >> 8;          // K-half
  const int gi   = row >> 6;          // gate 0..3
  const int uo   = row & 63;          // unit within slice
  const int grow = gi * 256 + rk * 64 + uo;
  const int wv   = tid >> 6;          // wave 0..7
  const int lane = tid & 63;

  const float* Wih = dir ? Wih_b : Wih_f;
  const float* Whh = dir ? Whh_b : Whh_f;
  const float* bih = dir ? bih_b : bih_f;
  const float* bhh = dir ? bhh_b : bhh_f;

  // 48 float4 = 192 weight VGPRs (compile-time indexed -> registers)
  float4 wreg[48];
  if (kh == 0) {
#pragma unroll
    for (int c = 0; c < 48; ++c)
      wreg[c] = *(const float4*)(Whh + (size_t)grow * 256 + c * 4);
  } else {
#pragma unroll
    for (int c = 0; c < 16; ++c)
      wreg[c] = *(const float4*)(Whh + (size_t)grow * 256 + 192 + c * 4);
#pragma unroll
    for (int c = 0; c < 32; ++c)
      wreg[16 + c] = *(const float4*)(Wih + (size_t)grow * 128 + c * 4);
  }
  const int vb = kh ? 192 : 0;        // v base (wave-uniform)

  __shared__ float vlds[BQ][384];     // 3 KB : [h(256) | emb(128)] per batch
  __shared__ float red[2][2][BQ][256];// 8 KB : [parity][kh][b][row]

  const bool isgate = (wv >= 6);
  float bias4[4] = {0, 0, 0, 0};
  float creg = 0.0f;
  int gb = 0;
  if (isgate) {
    gb = (tid - 384) >> 6;            // wave6 -> batch 0, wave7 -> batch 1
#pragma unroll
    for (int gg = 0; gg < 4; ++gg) {
      int rr = gg * 256 + rk * 64 + lane;
      bias4[gg] = bih[rr] + bhh[rr];
    }
    creg = c0[(size_t)(dir * BATCH + b0 + gb) * HID + rk * 64 + lane];
  }

  // emb staging role (tid<256): batch eb, element ee
  const int eb = tid >> 7, ee = tid & 127;
  float ev = 0.0f; int xv = 0;
  if (tid < 256) {
    ev = embed[(size_t)x[(b0 + eb) * SLEN + (dir ? SLEN - 1 : 0)] * EMB + ee];
    xv = x[(b0 + eb) * SLEN + (dir ? SLEN - 2 : 1)];
  }

  for (int it = 0; it < SLEN; ++it) {
    const int t = dir ? (SLEN - 1 - it) : it;

    if (!isgate) {
      // ---- stage emb(t) ---------------------------------------------------
      if (tid < 256) vlds[eb][256 + ee] = ev;
      // ---- poll flag line + fetch h(t-1) (waves 0-5; 512 words) ----------
      if (it == 0) {
        const float* hs = h0 + (size_t)(dir * BATCH + b0) * HID;  // 512 contig
        vlds[tid >> 8][tid & 255] = hs[tid];
        if (tid < 128) vlds[1][tid + 128] = hs[tid + 384];
      } else {
        const u32* fp = flags + ((size_t)g * SLEN + (it - 1)) * NFLAG + (lane & 7);
        u32 v = aload(fp);
        int sp = 0;
        while (!__all(v != 0) && ++sp < (1 << 14)) {
          __builtin_amdgcn_s_sleep(1);
          v = aload(fp);
        }
        asm volatile("" ::: "memory");   // no hoisting of h loads above detect
        const int tp = dir ? (t + 1) : (t - 1);
        const u32* hs = (const u32*)(h_hist +
                         ((size_t)(dir * SLEN + tp) * BATCH + b0) * HID);
        u32 a0 = aload(hs + tid);
        u32 a1 = (tid < 128) ? aload(hs + tid + 384) : 0u;
        *(u32*)&vlds[tid >> 8][tid & 255] = a0;
        if (tid < 128) *(u32*)&vlds[1][tid + 128] = a1;
      }
    }
    __syncthreads();                                   // SYNC_A

    // ---- deep prefetch: emb(it+1), x(it+2) (overlaps GEMM) ---------------
    if (tid < 256) {
      ev = embed[(size_t)xv * EMB + ee];
      int sn = it + 2 < SLEN ? it + 2 : SLEN - 1;
      xv = x[(b0 + eb) * SLEN + (dir ? (SLEN - 1 - sn) : sn)];
    }

    // ---- GEMM: one gate-row x K-half, 2 batches (broadcast LDS reads) ----
    float a0 = 0.0f, a1 = 0.0f;
#pragma unroll
    for (int c = 0; c < 48; ++c) {
      float4 w4 = wreg[c];
      float4 v0 = *(const float4*)&vlds[0][vb + c * 4];
      float4 v1 = *(const float4*)&vlds[1][vb + c * 4];
      a0 = fmaf(w4.x, v0.x, a0); a0 = fmaf(w4.y, v0.y, a0);
      a0 = fmaf(w4.z, v0.z, a0); a0 = fmaf(w4.w, v0.w, a0);
      a1 = fmaf(w4.x, v1.x, a1); a1 = fmaf(w4.y, v1.y, a1);
      a1 = fmaf(w4.z, v1.z, a1); a1 = fmaf(w4.w, v1.w, a1);
    }
    red[it & 1][kh][0][row] = a0;
    red[it & 1][kh][1][row] = a1;
    __syncthreads();                                   // SYNC_B

    // ---- gates + state + publish (waves 6,7) -----------------------------
    if (isgate) {
      const int p = it & 1;
      float s0 = bias4[0] + red[p][0][gb][lane]       + red[p][1][gb][lane];
      float s1 = bias4[1] + red[p][0][gb][64 + lane]  + red[p][1][gb][64 + lane];
      float s2 = bias4[2] + red[p][0][gb][128 + lane] + red[p][1][gb][128 + lane];
      float s3 = bias4[3] + red[p][0][gb][192 + lane] + red[p][1][gb][192 + lane];
      float ig = sigmoidf_(s0);
      float fg = sigmoidf_(s1);
      float gv = tanhf(s2);
      float og = sigmoidf_(s3);
      creg = fg * creg + ig * gv;
      float hv = og * tanhf(creg);
      __hip_atomic_store(h_hist + ((size_t)(dir * SLEN + t) * BATCH + (b0 + gb)) * HID
                           + rk * 64 + lane,
                         hv, __ATOMIC_RELAXED, __HIP_MEMORY_SCOPE_AGENT);
      asm volatile("s_waitcnt vmcnt(0)" ::: "memory");   // this wave's h committed
      if (lane == 0)
        __hip_atomic_store(flags + ((size_t)g * SLEN + it) * NFLAG + rk * 2 + (wv - 6),
                           1u, __ATOMIC_RELAXED, __HIP_MEMORY_SCOPE_AGENT);
    }
    // waves 0-5 proceed to next iteration immediately.
  }
}

// ---------------------------------------------------------------------------
// feats[s][b][tag] = [hf|hb] . Wc[tag] + bc[tag]
// grid = (512/4)*8 blocks (4 timesteps, 8-batch chunk), 256 threads.
// ---------------------------------------------------------------------------
__global__ __launch_bounds__(256) void feats_kernel(
    const float* __restrict__ h_hist, const float* __restrict__ Wc,
    const float* __restrict__ bc, float* __restrict__ feats)
{
  const int s0  = (blockIdx.x >> 3) * SB;
  const int b0  = (blockIdx.x & 7) * FB;
  const int tid = threadIdx.x;
  __shared__ float wc[NT * 516];    // 37.2 KB
  __shared__ float hl[FB * 516];    // 16.5 KB
  __shared__ float bcl[NT];
  if (tid < NT) bcl[tid] = bc[tid];
  for (int f = tid * 4; f < NT * 512; f += 1024) {
    float4 v = *(const float4*)(Wc + f);
    *(float4*)&wc[(f >> 9) * 516 + (f & 511)] = v;
  }
  for (int si = 0; si < SB; ++si) {
    const int s = s0 + si;
    const float* src0 = h_hist + ((size_t)s * BATCH + b0) * HID;
    const float* src1 = h_hist + ((size_t)(SLEN + s) * BATCH + b0) * HID;
    for (int f = tid * 4; f < FB * 256; f += 1024) {
      int b = f >> 8, j = f & 255;
      *(float4*)&hl[b * 516 + j]       = *(const float4*)(src0 + f);
      *(float4*)&hl[b * 516 + 256 + j] = *(const float4*)(src1 + f);
    }
    __syncthreads();
    if (tid < FB * NT) {
      int b = tid / NT, tag = tid - b * NT;
      float a = bcl[tag];
      const float* hp = &hl[b * 516];
      const float* wp = &wc[tag * 516];
#pragma unroll 8
      for (int k = 0; k < 512; k += 4) {
        float4 h4 = *(const float4*)(hp + k);
        float4 w4 = *(const float4*)(wp + k);
        a = fmaf(h4.x, w4.x, a); a = fmaf(h4.y, w4.y, a);
        a = fmaf(h4.z, w4.z, a); a = fmaf(h4.w, w4.w, a);
      }
      feats[((size_t)s * BATCH + b0 + b) * NT + tag] = a;
    }
    __syncthreads();   // WAR guard before restaging hl
  }
}

// ---------------------------------------------------------------------------
// Viterbi + backtrace, one block per batch, 64 threads (lanes 0..17 active).
// Replicates reference exactly, including add order:
//   cur = (feats[to] + trans[from][to]) + partition[from];  new_p = max(cur)
// strict > keeps the FIRST max (matches jnp.argmax). Masked bp=0, snapshot at
// t=len-1, back[len-1]=pointer overwrite, decode[S-1]=pointer.
// ---------------------------------------------------------------------------
__global__ __launch_bounds__(64) void viterbi_kernel(
    const float* __restrict__ feats, const int* __restrict__ mask,
    const float* __restrict__ trans, float* __restrict__ out)
{
  const int b = blockIdx.x;
  const int lane = threadIdx.x;
  __shared__ float tr[NT][NT + 1];
  __shared__ float part[2][NT + 2];
  __shared__ float lastp[NT + 2];
  __shared__ unsigned char bp[SLEN][20];
  __shared__ int len_s;

  for (int f = lane; f < NT * NT; f += 64) tr[f / NT][f % NT] = trans[f];
  int m = 0;
#pragma unroll
  for (int i = 0; i < 8; ++i) m += mask[b * SLEN + lane * 8 + i];
  for (int off = 32; off; off >>= 1) m += __shfl_down(m, off);
  if (lane == 0) len_s = m;
  __syncthreads();
  const int len = len_s;

  if (lane < NT) part[0][lane] = feats[(size_t)b * NT + lane] + tr[16][lane];  // START=16
  __syncthreads();

  int cur = 0;
  float fnext = (lane < NT) ? feats[((size_t)BATCH + b) * NT + lane] : 0.0f;
  int   mnext = mask[b * SLEN + 1];
  for (int t = 1; t < SLEN; ++t) {
    float fcur = fnext; int mcur = mnext;
    if (t < SLEN - 1) {
      fnext = (lane < NT) ? feats[((size_t)(t + 1) * BATCH + b) * NT + lane] : 0.0f;
      mnext = mask[b * SLEN + t + 1];
    }
    if (lane < NT) {
      float best = -3.0e38f; int bf = 0;
#pragma unroll
      for (int from = 0; from < NT; ++from) {
        float v = (fcur + tr[from][lane]) + part[cur][from];  // exact ref order
        if (v > best) { best = v; bf = from; }
      }
      part[cur ^ 1][lane] = best;          // new_p includes feats (ref semantics)
      bp[t][lane] = mcur ? (unsigned char)bf : (unsigned char)0;
      if (t == len - 1) lastp[lane] = best;
    }
    cur ^= 1;
    __syncthreads();
  }

  if (lane == 0) {
    float best = -3.0e38f; int bf = 0;
    for (int from = 0; from < NT; ++from) {
      float v = lastp[from] + tr[from][17];      // END=17
      if (v > best) { best = v; bf = from; }
    }
    out[b] = best;                                // path_score
    int ptr = bf;
    out[BATCH + (size_t)b * SLEN + (SLEN - 1)] = (float)ptr;
    for (int i = SLEN - 2; i >= 0; --i) {
      int nw = (i == len - 1) ? bf : (int)bp[i + 1][ptr];
      out[BATCH + (size_t)b * SLEN + i] = (float)nw;
      ptr = nw;
    }
  }
}

// ---------------------------------------------------------------------------
extern "C" void kernel_launch(void* const* d_in, const int* in_sizes, int n_in,
                              void* d_out, int out_size, void* d_ws, size_t ws_size,
                              hipStream_t stream) {
  const int*   x      = (const int*)  d_in[0];
  const int*   mask   = (const int*)  d_in[1];
  const float* embed  = (const float*)d_in[2];
  const float* Wih_f  = (const float*)d_in[3];
  const float* Whh_f  = (const float*)d_in[4];
  const float* bih_f  = (const float*)d_in[5];
  const float* bhh_f  = (const float*)d_in[6];
  const float* Wih_b  = (const float*)d_in[7];
  const float* Whh_b  = (const float*)d_in[8];
  const float* bih_b  = (const float*)d_in[9];
  const float* bhh_b  = (const float*)d_in[10];
  const float* Wc     = (const float*)d_in[11];
  const float* bc     = (const float*)d_in[12];
  const float* trans  = (const float*)d_in[13];
  const float* h0     = (const float*)d_in[14];
  const float* c0     = (const float*)d_in[15];
  float* out = (float*)d_out;

  // ws layout: h_hist @0 (64MB); flags and feats SHARE ws+64MB (disjoint in
  // time; flags re-zeroed each launch -> graph-replay deterministic).
  char* ws = (char*)d_ws;
  float* h_hist = (float*)ws;                                 // 64 MB
  u32*   flags  = (u32*)(ws + (size_t)67108864);              // 1 MB
  float* feats  = (float*)(ws + (size_t)67108864);            // 2.25 MB (aliases flags)

  hipMemsetAsync(flags, 0, (size_t)NGROUP * SLEN * NFLAG * sizeof(u32), stream);
  lstm_kernel<<<256, 512, 0, stream>>>(x, embed, Wih_f, Whh_f, bih_f, bhh_f,
                                       Wih_b, Whh_b, bih_b, bhh_b, h0, c0,
                                       h_hist, flags);
  feats_kernel<<<(SLEN / SB) * 8, 256, 0, stream>>>(h_hist, Wc, bc, feats);
  viterbi_kernel<<<BATCH, 64, 0, stream>>>(feats, mask, trans, out);
}

// Round 12
// 2072.178 us; speedup vs baseline: 2.1556x; 1.0411x over previous
//
#include <hip/hip_runtime.h>

#define SLEN 512
#define BATCH 64
#define HID 256
#define EMB 128
#define NT 18
#define NCHAIN 128        // 2 dirs x 64 batches
#define FB 8              // batches per feats block
#define SB 4              // timesteps per feats block

typedef unsigned int u32;

__device__ __forceinline__ float sigmoidf_(float v) { return 1.0f / (1.0f + expf(-v)); }
__device__ __forceinline__ u32 aload(const u32* p) {
  return __hip_atomic_load((u32*)p, __ATOMIC_RELAXED, __HIP_MEMORY_SCOPE_AGENT);
}

// ---------------------------------------------------------------------------
// Persistent bidirectional LSTM, TWO-CHAIN INTERLEAVE.
// grid = 256 blocks x 512 threads (launch_bounds(512,2): 2 waves/SIMD ->
// exactly 1 block/CU, 256 blocks co-resident).
// blockIdx: rk = blockIdx>>6 (slice 0..3, units [64rk,64rk+64) = 256 gate
// rows); q = blockIdx&63: dir = q>>5, batches bA = 2*(q&31), bB = bA+1.
// Two chains (dir,bA),(dir,bB) share the SAME weight registers.
// Thread: row = tid&255 (gate row), kh = tid>>8 (K-half: h 0..191 | h 192..255
// + emb). 48 float4 weights in VGPRs. All GEMM LDS reads are wave-uniform
// broadcasts; gates/store/fetch are unit-stride. Zero bank conflicts.
//
// Per iteration (chains A,B each advance one step t):
//   GEMM A -> S1
//   [w6: gates A -> h stores -> vmcnt(0) -> flag A(it)]
//   [w0-3: poll flag B(it-1) (wave w polls ONLY slice w's word, broadcast),
//          fetch slice w's 64 h words, stage vB]
//   [w4,5: stage emb_B(t), prefetch emb_B(t+1)]            -> S2
//   GEMM B -> S3
//   [w7: gates B -> flag B(it)] [w0-3: poll A(it), fetch, stage vA]
//   [w4,5: stage emb_A(t+1), prefetch]                     -> S4
// Each publish->poll gap spans a GEMM+exchange phase (~2k cyc) so drains and
// IC visibility complete off the critical path; fetch RT overlaps gates.
// ---------------------------------------------------------------------------
__global__ __launch_bounds__(512, 2) void lstm_kernel(
    const int* __restrict__ x, const float* __restrict__ embed,
    const float* __restrict__ Wih_f, const float* __restrict__ Whh_f,
    const float* __restrict__ bih_f, const float* __restrict__ bhh_f,
    const float* __restrict__ Wih_b, const float* __restrict__ Whh_b,
    const float* __restrict__ bih_b, const float* __restrict__ bhh_b,
    const float* __restrict__ h0, const float* __restrict__ c0,
    float* __restrict__ h_hist, u32* __restrict__ flags)
{
  const int rk   = blockIdx.x >> 6;   // slice 0..3
  const int q    = blockIdx.x & 63;
  const int dir  = q >> 5;
  const int bA   = (q & 31) * 2, bB = bA + 1;
  const int chA  = dir * BATCH + bA, chB = chA + 1;
  const int tid  = threadIdx.x;       // 0..511
  const int row  = tid & 255;
  const int kh   = tid >> 8;
  const int gi   = row >> 6;
  const int uo   = row & 63;
  const int grow = gi * 256 + rk * 64 + uo;
  const int wv   = tid >> 6;          // wave 0..7
  const int lane = tid & 63;

  const float* Wih = dir ? Wih_b : Wih_f;
  const float* Whh = dir ? Whh_b : Whh_f;
  const float* bih = dir ? bih_b : bih_f;
  const float* bhh = dir ? bhh_b : bhh_f;

  // 48 float4 = 192 weight VGPRs
  float4 wreg[48];
  if (kh == 0) {
#pragma unroll
    for (int c = 0; c < 48; ++c)
      wreg[c] = *(const float4*)(Whh + (size_t)grow * 256 + c * 4);
  } else {
#pragma unroll
    for (int c = 0; c < 16; ++c)
      wreg[c] = *(const float4*)(Whh + (size_t)grow * 256 + 192 + c * 4);
#pragma unroll
    for (int c = 0; c < 32; ++c)
      wreg[16 + c] = *(const float4*)(Wih + (size_t)grow * 128 + c * 4);
  }
  const int vb = kh ? 192 : 0;        // wave-uniform v base

  __shared__ float vA[384], vB[384];      // [h(256) | emb(128)] per chain
  __shared__ float redA[2][256], redB[2][256];

  // gate-wave state: w6 <-> chain A, w7 <-> chain B (same dir -> same bias)
  float bias4[4] = {0, 0, 0, 0};
  float creg = 0.0f;
  if (wv >= 6) {
    int b = (wv == 6) ? bA : bB;
#pragma unroll
    for (int gg = 0; gg < 4; ++gg) {
      int rr = gg * 256 + rk * 64 + lane;
      bias4[gg] = bih[rr] + bhh[rr];
    }
    creg = c0[(size_t)(dir * BATCH + b) * HID + rk * 64 + lane];
  }

  // timestep mapping with clamp
  auto TS = [&](int s) { s = s < SLEN ? s : SLEN - 1; return dir ? (SLEN - 1 - s) : s; };

  // emb prefetch registers (lanes 256..383: ee = tid-256)
  const int ee = tid - 256;
  float evA = 0.0f, evB = 0.0f;
  int xvA = 0, xvB = 0;

  // ---- prologue ----
  if (tid < 256) {
    vA[tid] = h0[(size_t)(dir * BATCH + bA) * HID + tid];
    vB[tid] = h0[(size_t)(dir * BATCH + bB) * HID + tid];
  } else if (tid < 384) {
    vA[256 + ee] = embed[(size_t)x[bA * SLEN + TS(0)] * EMB + ee];  // emb_A(0)
    evA = embed[(size_t)x[bA * SLEN + TS(1)] * EMB + ee];           // emb_A(1)
    xvA = x[bA * SLEN + TS(2)];
    evB = embed[(size_t)x[bB * SLEN + TS(0)] * EMB + ee];           // emb_B(0)
    xvB = x[bB * SLEN + TS(1)];
  }
  __syncthreads();

  for (int it = 0; it < SLEN; ++it) {
    const int t = dir ? (SLEN - 1 - it) : it;

    // ================= GEMM A =================
    {
      float acc = 0.0f;
#pragma unroll
      for (int c = 0; c < 48; ++c) {
        float4 w4 = wreg[c];
        float4 v4 = *(const float4*)&vA[vb + c * 4];   // broadcast
        acc = fmaf(w4.x, v4.x, acc); acc = fmaf(w4.y, v4.y, acc);
        acc = fmaf(w4.z, v4.z, acc); acc = fmaf(w4.w, v4.w, acc);
      }
      redA[kh][row] = acc;
    }
    __syncthreads();                                   // S1

    // ======== gates A (w6) || poll+fetch+stage B (w0-5) ========
    if (wv == 6) {
      float s0 = bias4[0] + redA[0][lane]       + redA[1][lane];
      float s1 = bias4[1] + redA[0][64 + lane]  + redA[1][64 + lane];
      float s2 = bias4[2] + redA[0][128 + lane] + redA[1][128 + lane];
      float s3 = bias4[3] + redA[0][192 + lane] + redA[1][192 + lane];
      float ig = sigmoidf_(s0), fg = sigmoidf_(s1);
      float gv = tanhf(s2),     og = sigmoidf_(s3);
      creg = fg * creg + ig * gv;
      float hv = og * tanhf(creg);
      __hip_atomic_store(h_hist + ((size_t)(dir * SLEN + t) * BATCH + bA) * HID
                           + rk * 64 + lane,
                         hv, __ATOMIC_RELAXED, __HIP_MEMORY_SCOPE_AGENT);
      asm volatile("s_waitcnt vmcnt(0)" ::: "memory");
      if (lane == 0)
        __hip_atomic_store(flags + ((size_t)chA * SLEN + it) * 4 + rk, 1u,
                           __ATOMIC_RELAXED, __HIP_MEMORY_SCOPE_AGENT);
    } else if (wv < 4) {
      if (it > 0) {
        const u32* fp = flags + ((size_t)chB * SLEN + (it - 1)) * 4 + wv;
        u32 v = aload(fp); int sp = 0;
        while (!__all(v != 0) && ++sp < (1 << 14)) {
          __builtin_amdgcn_s_sleep(1);
          v = aload(fp);
        }
        asm volatile("" ::: "memory");
        const int tp = dir ? (t + 1) : (t - 1);
        u32 hw = aload((const u32*)(h_hist +
                    ((size_t)(dir * SLEN + tp) * BATCH + bB) * HID) + tid);
        *(u32*)&vB[tid] = hw;
      }
    } else if (wv < 6) {
      vB[256 + ee] = evB;                              // emb_B(t)
      evB = embed[(size_t)xvB * EMB + ee];             // emb_B(t+1)
      xvB = x[bB * SLEN + TS(it + 2)];
    }
    __syncthreads();                                   // S2

    // ================= GEMM B =================
    {
      float acc = 0.0f;
#pragma unroll
      for (int c = 0; c < 48; ++c) {
        float4 w4 = wreg[c];
        float4 v4 = *(const float4*)&vB[vb + c * 4];   // broadcast
        acc = fmaf(w4.x, v4.x, acc); acc = fmaf(w4.y, v4.y, acc);
        acc = fmaf(w4.z, v4.z, acc); acc = fmaf(w4.w, v4.w, acc);
      }
      redB[kh][row] = acc;
    }
    __syncthreads();                                   // S3

    // ======== gates B (w7) || poll+fetch+stage A (w0-5) ========
    if (wv == 7) {
      float s0 = bias4[0] + redB[0][lane]       + redB[1][lane];
      float s1 = bias4[1] + redB[0][64 + lane]  + redB[1][64 + lane];
      float s2 = bias4[2] + redB[0][128 + lane] + redB[1][128 + lane];
      float s3 = bias4[3] + redB[0][192 + lane] + redB[1][192 + lane];
      float ig = sigmoidf_(s0), fg = sigmoidf_(s1);
      float gv = tanhf(s2),     og = sigmoidf_(s3);
      creg = fg * creg + ig * gv;
      float hv = og * tanhf(creg);
      __hip_atomic_store(h_hist + ((size_t)(dir * SLEN + t) * BATCH + bB) * HID
                           + rk * 64 + lane,
                         hv, __ATOMIC_RELAXED, __HIP_MEMORY_SCOPE_AGENT);
      asm volatile("s_waitcnt vmcnt(0)" ::: "memory");
      if (lane == 0)
        __hip_atomic_store(flags + ((size_t)chB * SLEN + it) * 4 + rk, 1u,
                           __ATOMIC_RELAXED, __HIP_MEMORY_SCOPE_AGENT);
    } else if (wv < 4) {
      if (it < SLEN - 1) {
        const u32* fp = flags + ((size_t)chA * SLEN + it) * 4 + wv;
        u32 v = aload(fp); int sp = 0;
        while (!__all(v != 0) && ++sp < (1 << 14)) {
          __builtin_amdgcn_s_sleep(1);
          v = aload(fp);
        }
        asm volatile("" ::: "memory");
        u32 hw = aload((const u32*)(h_hist +
                    ((size_t)(dir * SLEN + t) * BATCH + bA) * HID) + tid);
        *(u32*)&vA[tid] = hw;
      }
    } else if (wv < 6) {
      if (it < SLEN - 1) {
        vA[256 + ee] = evA;                            // emb_A(t+1)
        evA = embed[(size_t)xvA * EMB + ee];           // emb_A(t+2)
        xvA = x[bA * SLEN + TS(it + 3)];
      }
    }
    __syncthreads();                                   // S4
  }
}

// ---------------------------------------------------------------------------
// feats[s][b][tag] = [hf|hb] . Wc[tag] + bc[tag]
// grid = (512/4)*8 blocks (4 timesteps, 8-batch chunk), 256 threads.
// ---------------------------------------------------------------------------
__global__ __launch_bounds__(256) void feats_kernel(
    const float* __restrict__ h_hist, const float* __restrict__ Wc,
    const float* __restrict__ bc, float* __restrict__ feats)
{
  const int s0  = (blockIdx.x >> 3) * SB;
  const int b0  = (blockIdx.x & 7) * FB;
  const int tid = threadIdx.x;
  __shared__ float wc[NT * 516];    // 37.2 KB
  __shared__ float hl[FB * 516];    // 16.5 KB
  __shared__ float bcl[NT];
  if (tid < NT) bcl[tid] = bc[tid];
  for (int f = tid * 4; f < NT * 512; f += 1024) {
    float4 v = *(const float4*)(Wc + f);
    *(float4*)&wc[(f >> 9) * 516 + (f & 511)] = v;
  }
  for (int si = 0; si < SB; ++si) {
    const int s = s0 + si;
    const float* src0 = h_hist + ((size_t)s * BATCH + b0) * HID;
    const float* src1 = h_hist + ((size_t)(SLEN + s) * BATCH + b0) * HID;
    for (int f = tid * 4; f < FB * 256; f += 1024) {
      int b = f >> 8, j = f & 255;
      *(float4*)&hl[b * 516 + j]       = *(const float4*)(src0 + f);
      *(float4*)&hl[b * 516 + 256 + j] = *(const float4*)(src1 + f);
    }
    __syncthreads();
    if (tid < FB * NT) {
      int b = tid / NT, tag = tid - b * NT;
      float a = bcl[tag];
      const float* hp = &hl[b * 516];
      const float* wp = &wc[tag * 516];
#pragma unroll 8
      for (int k = 0; k < 512; k += 4) {
        float4 h4 = *(const float4*)(hp + k);
        float4 w4 = *(const float4*)(wp + k);
        a = fmaf(h4.x, w4.x, a); a = fmaf(h4.y, w4.y, a);
        a = fmaf(h4.z, w4.z, a); a = fmaf(h4.w, w4.w, a);
      }
      feats[((size_t)s * BATCH + b0 + b) * NT + tag] = a;
    }
    __syncthreads();   // WAR guard before restaging hl
  }
}

// ---------------------------------------------------------------------------
// Viterbi + backtrace, one block per batch, 64 threads (lanes 0..17 active).
// Replicates reference exactly, including add order:
//   cur = (feats[to] + trans[from][to]) + partition[from];  new_p = max(cur)
// strict > keeps the FIRST max (matches jnp.argmax). Masked bp=0, snapshot at
// t=len-1, back[len-1]=pointer overwrite, decode[S-1]=pointer.
// ---------------------------------------------------------------------------
__global__ __launch_bounds__(64) void viterbi_kernel(
    const float* __restrict__ feats, const int* __restrict__ mask,
    const float* __restrict__ trans, float* __restrict__ out)
{
  const int b = blockIdx.x;
  const int lane = threadIdx.x;
  __shared__ float tr[NT][NT + 1];
  __shared__ float part[2][NT + 2];
  __shared__ float lastp[NT + 2];
  __shared__ unsigned char bp[SLEN][20];
  __shared__ int len_s;

  for (int f = lane; f < NT * NT; f += 64) tr[f / NT][f % NT] = trans[f];
  int m = 0;
#pragma unroll
  for (int i = 0; i < 8; ++i) m += mask[b * SLEN + lane * 8 + i];
  for (int off = 32; off; off >>= 1) m += __shfl_down(m, off);
  if (lane == 0) len_s = m;
  __syncthreads();
  const int len = len_s;

  if (lane < NT) part[0][lane] = feats[(size_t)b * NT + lane] + tr[16][lane];  // START=16
  __syncthreads();

  int cur = 0;
  float fnext = (lane < NT) ? feats[((size_t)BATCH + b) * NT + lane] : 0.0f;
  int   mnext = mask[b * SLEN + 1];
  for (int t = 1; t < SLEN; ++t) {
    float fcur = fnext; int mcur = mnext;
    if (t < SLEN - 1) {
      fnext = (lane < NT) ? feats[((size_t)(t + 1) * BATCH + b) * NT + lane] : 0.0f;
      mnext = mask[b * SLEN + t + 1];
    }
    if (lane < NT) {
      float best = -3.0e38f; int bf = 0;
#pragma unroll
      for (int from = 0; from < NT; ++from) {
        float v = (fcur + tr[from][lane]) + part[cur][from];  // exact ref order
        if (v > best) { best = v; bf = from; }
      }
      part[cur ^ 1][lane] = best;          // new_p includes feats (ref semantics)
      bp[t][lane] = mcur ? (unsigned char)bf : (unsigned char)0;
      if (t == len - 1) lastp[lane] = best;
    }
    cur ^= 1;
    __syncthreads();
  }

  if (lane == 0) {
    float best = -3.0e38f; int bf = 0;
    for (int from = 0; from < NT; ++from) {
      float v = lastp[from] + tr[from][17];      // END=17
      if (v > best) { best = v; bf = from; }
    }
    out[b] = best;                                // path_score
    int ptr = bf;
    out[BATCH + (size_t)b * SLEN + (SLEN - 1)] = (float)ptr;
    for (int i = SLEN - 2; i >= 0; --i) {
      int nw = (i == len - 1) ? bf : (int)bp[i + 1][ptr];
      out[BATCH + (size_t)b * SLEN + i] = (float)nw;
      ptr = nw;
    }
  }
}

// ---------------------------------------------------------------------------
extern "C" void kernel_launch(void* const* d_in, const int* in_sizes, int n_in,
                              void* d_out, int out_size, void* d_ws, size_t ws_size,
                              hipStream_t stream) {
  const int*   x      = (const int*)  d_in[0];
  const int*   mask   = (const int*)  d_in[1];
  const float* embed  = (const float*)d_in[2];
  const float* Wih_f  = (const float*)d_in[3];
  const float* Whh_f  = (const float*)d_in[4];
  const float* bih_f  = (const float*)d_in[5];
  const float* bhh_f  = (const float*)d_in[6];
  const float* Wih_b  = (const float*)d_in[7];
  const float* Whh_b  = (const float*)d_in[8];
  const float* bih_b  = (const float*)d_in[9];
  const float* bhh_b  = (const float*)d_in[10];
  const float* Wc     = (const float*)d_in[11];
  const float* bc     = (const float*)d_in[12];
  const float* trans  = (const float*)d_in[13];
  const float* h0     = (const float*)d_in[14];
  const float* c0     = (const float*)d_in[15];
  float* out = (float*)d_out;

  // ws layout: h_hist @0 (64MB); flags and feats SHARE ws+64MB (disjoint in
  // time; flags re-zeroed each launch -> graph-replay deterministic).
  char* ws = (char*)d_ws;
  float* h_hist = (float*)ws;                                 // 64 MB
  u32*   flags  = (u32*)(ws + (size_t)67108864);              // 1 MB
  float* feats  = (float*)(ws + (size_t)67108864);            // 2.25 MB (aliases flags)

  hipMemsetAsync(flags, 0, (size_t)NCHAIN * SLEN * 4 * sizeof(u32), stream);
  lstm_kernel<<<256, 512, 0, stream>>>(x, embed, Wih_f, Whh_f, bih_f, bhh_f,
                                       Wih_b, Whh_b, bih_b, bhh_b, h0, c0,
                                       h_hist, flags);
  feats_kernel<<<(SLEN / SB) * 8, 256, 0, stream>>>(h_hist, Wc, bc, feats);
  viterbi_kernel<<<BATCH, 64, 0, stream>>>(feats, mask, trans, out);
}